// Round 1
// baseline (327.129 us; speedup 1.0000x reference)
//
#include <hip/hip_runtime.h>
#include <math.h>

#define BB 8
#define SS 160
#define HH 768
#define DEPTH 64
#define NHEAD 12
#define DHEAD 64
#define BS (BB*SS)

constexpr float W_EDGE_C = 1.0f;
constexpr float EPS_C = 1e-5f;

// ---------------- Projection: q,k,v = X @ W + b ----------------
// Block: 16 rows x 256 cols of one of {Wq,Wk,Wv}. X tile transposed in LDS so
// the 16 row-values per input channel are contiguous (float4 broadcast reads).
__global__ __launch_bounds__(256) void proj_qkv(
    const float* __restrict__ X,
    const float* __restrict__ Wq, const float* __restrict__ bq,
    const float* __restrict__ Wk, const float* __restrict__ bk,
    const float* __restrict__ Wv, const float* __restrict__ bv,
    float* __restrict__ q, float* __restrict__ k, float* __restrict__ v)
{
    __shared__ float sxT[HH * 16];   // 48 KB: sxT[c*16 + r]
    int bx = blockIdx.x;
    int rt = bx / 9, rem = bx % 9;
    int m = rem / 3, ct = rem % 3;
    int row0 = rt * 16;
    const float* W    = (m == 0) ? Wq : (m == 1) ? Wk : Wv;
    const float* bias = (m == 0) ? bq : (m == 1) ? bk : bv;
    float* out        = (m == 0) ? q  : (m == 1) ? k  : v;

    for (int idx = threadIdx.x; idx < 16 * HH; idx += 256) {
        int r = idx / HH, c = idx - r * HH;
        sxT[c * 16 + r] = X[(row0 + r) * HH + c];
    }
    __syncthreads();

    int col = ct * 256 + threadIdx.x;
    float acc[16];
#pragma unroll
    for (int r = 0; r < 16; r++) acc[r] = 0.f;

    const float* Wp = W + col;
    for (int c = 0; c < HH; c++) {
        float wv = Wp[(size_t)c * HH];
        const float4* xp = (const float4*)(&sxT[c * 16]);
        float4 x0 = xp[0], x1 = xp[1], x2 = xp[2], x3 = xp[3];
        acc[0]  += x0.x * wv;  acc[1]  += x0.y * wv;
        acc[2]  += x0.z * wv;  acc[3]  += x0.w * wv;
        acc[4]  += x1.x * wv;  acc[5]  += x1.y * wv;
        acc[6]  += x1.z * wv;  acc[7]  += x1.w * wv;
        acc[8]  += x2.x * wv;  acc[9]  += x2.y * wv;
        acc[10] += x2.z * wv;  acc[11] += x2.w * wv;
        acc[12] += x3.x * wv;  acc[13] += x3.y * wv;
        acc[14] += x3.z * wv;  acc[15] += x3.w * wv;
    }
    float bb = bias[col];
#pragma unroll
    for (int r = 0; r < 16; r++) out[(size_t)(row0 + r) * HH + col] = acc[r] + bb;
}

// ---------------- Fused attention + edge terms + LayerNorm ----------------
// One block per (b, i) query row. 256 threads = 4 waves.
__global__ __launch_bounds__(256) void attn_kernel(
    const float* __restrict__ token, const float* __restrict__ edge,
    const int* __restrict__ mask,
    const float* __restrict__ q_ws, const float* __restrict__ k_ws,
    const float* __restrict__ v_ws,
    const float* __restrict__ Wek, const float* __restrict__ bek,
    const float* __restrict__ Wev, const float* __restrict__ bev,
    const float* __restrict__ ln_g, const float* __restrict__ ln_b,
    float* __restrict__ out)
{
    __shared__ float s_q[HH];                 // q row
    __shared__ float s_qek[NHEAD][DEPTH];     // Wek_h^T q_h
    __shared__ float s_qbek[NHEAD];           // q_h . bek_h
    __shared__ float s_scores[NHEAD][SS];     // scores -> probs
    __shared__ float s_accv[4][HH];           // per-wave partial p.v
    __shared__ float s_pe4[4][HH];            // per-wave partial p.e  (pe[h][d])
    __shared__ float s_x[HH];                 // pre-LN row
    __shared__ float s_red[8];

    int bi = blockIdx.x;                      // b*S + i
    int b  = bi / SS;
    int tid = threadIdx.x;
    int w = tid >> 6, l = tid & 63;

    // ---- load q row ----
    for (int c = tid; c < HH; c += 256) s_q[c] = q_ws[(size_t)bi * HH + c];
    __syncthreads();

    // ---- qek[h][d] = sum_c q[h*64+c] * Wek[d][h*64+c] ----
    for (int mdx = tid; mdx < NHEAD * DEPTH; mdx += 256) {
        int h = mdx >> 6, d = mdx & 63;
        const float* wp = Wek + (size_t)d * HH + h * DHEAD;
        const float* qp = s_q + h * DHEAD;
        float sum = 0.f;
#pragma unroll
        for (int c = 0; c < DHEAD; c++) sum += qp[c] * wp[c];
        s_qek[h][d] = sum;
    }
    // qbek[h] = q_h . bek_h  (wave w handles heads w, w+4, w+8)
    for (int h = w; h < NHEAD; h += 4) {
        float p = s_q[h * DHEAD + l] * bek[h * DHEAD + l];
#pragma unroll
        for (int mm = 32; mm >= 1; mm >>= 1) p += __shfl_xor(p, mm, 64);
        if (l == 0) s_qbek[h] = p;
    }
    __syncthreads();

    // per-lane registers: channel l of each head
    float q_reg[NHEAD], qek_reg[NHEAD];
#pragma unroll
    for (int h = 0; h < NHEAD; h++) {
        q_reg[h]   = s_q[h * DHEAD + l];
        qek_reg[h] = s_qek[h][l];
    }

    // ---- pass 1: scores[h][j] ----
    for (int j = w; j < SS; j += 4) {
        float e_val = edge[(((size_t)bi) * SS + j) * DEPTH + l];
        const float* kp = k_ws + ((size_t)(b * SS + j)) * HH + l;
        float part[NHEAD];
#pragma unroll
        for (int h = 0; h < NHEAD; h++) {
            float kk = kp[h * DHEAD];
            part[h] = q_reg[h] * kk + W_EDGE_C * (qek_reg[h] * e_val);
        }
#pragma unroll
        for (int mm = 1; mm < 64; mm <<= 1) {
#pragma unroll
            for (int h = 0; h < NHEAD; h++) part[h] += __shfl_xor(part[h], mm, 64);
        }
        if (l == 0) {
            int mk = mask[(size_t)bi * SS + j];
#pragma unroll
            for (int h = 0; h < NHEAD; h++)
                s_scores[h][j] = mk ? (part[h] + W_EDGE_C * s_qbek[h]) * 0.125f
                                    : -10000.0f;
        }
    }
    __syncthreads();

    // ---- softmax per head (wave w -> heads w, w+4, w+8); S=160 = 64+64+32 ----
    for (int h = w; h < NHEAD; h += 4) {
        float v0 = s_scores[h][l];
        float v1 = s_scores[h][l + 64];
        float v2 = (l < 32) ? s_scores[h][l + 128] : -INFINITY;
        float mx = fmaxf(v0, fmaxf(v1, v2));
#pragma unroll
        for (int mm = 32; mm >= 1; mm >>= 1) mx = fmaxf(mx, __shfl_xor(mx, mm, 64));
        float e0 = expf(v0 - mx), e1 = expf(v1 - mx);
        float e2 = (l < 32) ? expf(v2 - mx) : 0.f;
        float sm = e0 + e1 + e2;
#pragma unroll
        for (int mm = 32; mm >= 1; mm >>= 1) sm += __shfl_xor(sm, mm, 64);
        float inv = 1.0f / sm;
        s_scores[h][l]      = e0 * inv;
        s_scores[h][l + 64] = e1 * inv;
        if (l < 32) s_scores[h][l + 128] = e2 * inv;
    }
    __syncthreads();

    // ---- pass 2: ctx_v[h][c] = sum_j p*v ; pe[h][d] = sum_j p*e ----
    float accv[NHEAD], acce[NHEAD];
#pragma unroll
    for (int h = 0; h < NHEAD; h++) { accv[h] = 0.f; acce[h] = 0.f; }
    for (int j = w; j < SS; j += 4) {
        float e_val = edge[(((size_t)bi) * SS + j) * DEPTH + l];
        const float* vp = v_ws + ((size_t)(b * SS + j)) * HH + l;
#pragma unroll
        for (int h = 0; h < NHEAD; h++) {
            float p = s_scores[h][j];
            accv[h] += p * vp[h * DHEAD];
            acce[h] += p * e_val;
        }
    }
#pragma unroll
    for (int h = 0; h < NHEAD; h++) {
        s_accv[w][h * DHEAD + l] = accv[h];
        s_pe4[w][h * DHEAD + l]  = acce[h];
    }
    __syncthreads();
    // deterministic 4-wave combine
    for (int c = tid; c < HH; c += 256) {
        s_accv[0][c] = s_accv[0][c] + s_accv[1][c] + s_accv[2][c] + s_accv[3][c];
        s_pe4[0][c]  = s_pe4[0][c]  + s_pe4[1][c]  + s_pe4[2][c]  + s_pe4[3][c];
    }
    __syncthreads();

    // ---- ctx_e = pe_h @ Wev_h + bev ; residual add ----
    for (int mdx = tid; mdx < HH; mdx += 256) {
        int h = mdx >> 6;
        const float* pep = &s_pe4[0][h * DHEAD];
        float sum = 0.f;
#pragma unroll
        for (int d = 0; d < DEPTH; d++) sum += pep[d] * Wev[(size_t)d * HH + mdx];
        float ctx = s_accv[0][mdx] + W_EDGE_C * (sum + bev[mdx]);
        s_x[mdx] = token[(size_t)bi * HH + mdx] + ctx;
    }
    __syncthreads();

    // ---- LayerNorm over H ----
    float lsum = 0.f, lsq = 0.f;
    for (int c = tid; c < HH; c += 256) {
        float x = s_x[c];
        lsum += x; lsq += x * x;
    }
#pragma unroll
    for (int mm = 32; mm >= 1; mm >>= 1) {
        lsum += __shfl_xor(lsum, mm, 64);
        lsq  += __shfl_xor(lsq,  mm, 64);
    }
    if (l == 0) { s_red[w] = lsum; s_red[4 + w] = lsq; }
    __syncthreads();
    float tsum = s_red[0] + s_red[1] + s_red[2] + s_red[3];
    float tsq  = s_red[4] + s_red[5] + s_red[6] + s_red[7];
    float mu  = tsum / HH;
    float var = tsq / HH - mu * mu;
    float rstd = rsqrtf(var + EPS_C);
    for (int c = tid; c < HH; c += 256)
        out[(size_t)bi * HH + c] = (s_x[c] - mu) * rstd * ln_g[c] + ln_b[c];
}

extern "C" void kernel_launch(void* const* d_in, const int* in_sizes, int n_in,
                              void* d_out, int out_size, void* d_ws, size_t ws_size,
                              hipStream_t stream) {
    const float* token = (const float*)d_in[0];
    const float* edge  = (const float*)d_in[1];
    const int*   mask  = (const int*)d_in[2];
    const float* Wq = (const float*)d_in[3];  const float* bq = (const float*)d_in[4];
    const float* Wk = (const float*)d_in[5];  const float* bk = (const float*)d_in[6];
    const float* Wv = (const float*)d_in[7];  const float* bv = (const float*)d_in[8];
    const float* Wek = (const float*)d_in[9];  const float* bek = (const float*)d_in[10];
    const float* Wev = (const float*)d_in[11]; const float* bev = (const float*)d_in[12];
    const float* ln_g = (const float*)d_in[13]; const float* ln_b = (const float*)d_in[14];
    float* out = (float*)d_out;

    float* q_ws = (float*)d_ws;
    float* k_ws = q_ws + (size_t)BS * HH;
    float* v_ws = k_ws + (size_t)BS * HH;

    // 80 row-tiles x 3 col-tiles x 3 matrices
    proj_qkv<<<720, 256, 0, stream>>>(token, Wq, bq, Wk, bk, Wv, bv,
                                      q_ws, k_ws, v_ws);
    attn_kernel<<<BS, 256, 0, stream>>>(token, edge, mask, q_ws, k_ws, v_ws,
                                        Wek, bek, Wev, bev, ln_g, ln_b, out);
}

// Round 2
// 230.360 us; speedup vs baseline: 1.4201x; 1.4201x over previous
//
#include <hip/hip_runtime.h>
#include <math.h>

#define BB 8
#define SS 160
#define HH 768
#define DEPTH 64
#define NHEAD 12
#define DHEAD 64
#define BS (BB*SS)

constexpr float EPS_C = 1e-5f;

// ---------------- Projection: q,k,v = X @ W + b ----------------
__global__ __launch_bounds__(256) void proj_qkv(
    const float* __restrict__ X,
    const float* __restrict__ Wq, const float* __restrict__ bq,
    const float* __restrict__ Wk, const float* __restrict__ bk,
    const float* __restrict__ Wv, const float* __restrict__ bv,
    float* __restrict__ q, float* __restrict__ k, float* __restrict__ v)
{
    __shared__ float sxT[HH * 16];   // 48 KB: sxT[c*16 + r]
    int bx = blockIdx.x;
    int rt = bx / 9, rem = bx % 9;
    int m = rem / 3, ct = rem % 3;
    int row0 = rt * 16;
    const float* W    = (m == 0) ? Wq : (m == 1) ? Wk : Wv;
    const float* bias = (m == 0) ? bq : (m == 1) ? bk : bv;
    float* out        = (m == 0) ? q  : (m == 1) ? k  : v;

    for (int idx = threadIdx.x; idx < 16 * HH; idx += 256) {
        int r = idx / HH, c = idx - r * HH;
        sxT[c * 16 + r] = X[(row0 + r) * HH + c];
    }
    __syncthreads();

    int col = ct * 256 + threadIdx.x;
    float acc[16];
#pragma unroll
    for (int r = 0; r < 16; r++) acc[r] = 0.f;

    const float* Wp = W + col;
    for (int c = 0; c < HH; c++) {
        float wv = Wp[(size_t)c * HH];
        const float4* xp = (const float4*)(&sxT[c * 16]);
        float4 x0 = xp[0], x1 = xp[1], x2 = xp[2], x3 = xp[3];
        acc[0]  += x0.x * wv;  acc[1]  += x0.y * wv;
        acc[2]  += x0.z * wv;  acc[3]  += x0.w * wv;
        acc[4]  += x1.x * wv;  acc[5]  += x1.y * wv;
        acc[6]  += x1.z * wv;  acc[7]  += x1.w * wv;
        acc[8]  += x2.x * wv;  acc[9]  += x2.y * wv;
        acc[10] += x2.z * wv;  acc[11] += x2.w * wv;
        acc[12] += x3.x * wv;  acc[13] += x3.y * wv;
        acc[14] += x3.z * wv;  acc[15] += x3.w * wv;
    }
    float bb = bias[col];
#pragma unroll
    for (int r = 0; r < 16; r++) out[(size_t)(row0 + r) * HH + col] = acc[r] + bb;
}

// ---------------- Fused attention + edge terms + LayerNorm ----------------
// One block per (b, i) query row. 256 threads = 4 waves. No cross-lane reduces
// in the hot paths: every score is a thread-serial dot product.
__global__ __launch_bounds__(256) void attn_kernel(
    const float* __restrict__ token, const float* __restrict__ edge,
    const int* __restrict__ mask,
    const float* __restrict__ q_ws, const float* __restrict__ k_ws,
    const float* __restrict__ v_ws,
    const float* __restrict__ Wek, const float* __restrict__ bek,
    const float* __restrict__ Wev, const float* __restrict__ bev,
    const float* __restrict__ ln_g, const float* __restrict__ ln_b,
    float* __restrict__ out)
{
    __shared__ float  s_q[HH];               // q row; reused as ctx_v after pass1
    __shared__ float  s_qek[NHEAD * DEPTH];  // [h][d] = Wek_h^T q_h
    __shared__ float  s_qbek[NHEAD];         // q_h . bek_h
    __shared__ float2 s_e2[64][33];          // e tile, float2-padded (stride 66 floats)
    __shared__ float  s_scores[NHEAD][SS];   // scores -> probs
    __shared__ float  s_pe[NHEAD][DEPTH];    // p . e
    __shared__ float  s_x[HH];               // pre-LN row
    __shared__ int    s_mask[SS];
    __shared__ float  s_red[8];

    int bi = blockIdx.x;                     // b*S + i
    int b  = bi / SS;
    int tid = threadIdx.x;
    int w = tid >> 6, l = tid & 63;

    // ---- load q row + mask row ----
    for (int c = tid; c < HH; c += 256) s_q[c] = q_ws[(size_t)bi * HH + c];
    if (tid < SS) s_mask[tid] = mask[(size_t)bi * SS + tid];
    __syncthreads();

    // ---- qek[h][d] = sum_c q[h*64+c] * Wek[d][h*64+c] ----
    for (int mdx = tid; mdx < NHEAD * DEPTH; mdx += 256) {
        int h = mdx >> 6, d = mdx & 63;
        const float* wp = Wek + (size_t)d * HH + h * DHEAD;
        const float* qp = s_q + h * DHEAD;
        float sum = 0.f;
#pragma unroll
        for (int c = 0; c < DHEAD; c += 4) {
            float4 qv = *(const float4*)(qp + c);
            float4 wv = *(const float4*)(wp + c);
            sum += qv.x * wv.x + qv.y * wv.y + qv.z * wv.z + qv.w * wv.w;
        }
        s_qek[mdx] = sum;
    }
    // qbek[h]: one thread per head, serial
    if (tid < NHEAD) {
        const float* qp = s_q + tid * DHEAD;
        const float* bp = bek + tid * DHEAD;
        float sum = 0.f;
#pragma unroll
        for (int c = 0; c < DHEAD; c++) sum += qp[c] * bp[c];
        s_qbek[tid] = sum;
    }

    const float* e_row = edge + (size_t)bi * SS * DEPTH;
    const float* k_b   = k_ws + (size_t)b * SS * HH;

    // ---- pass 1: scores, j-tiles of 64 ----
    for (int jt = 0; jt < SS; jt += 64) {
        int tl = (SS - jt < 64) ? (SS - jt) : 64;   // 64,64,32
        __syncthreads();   // covers qek/qbek on first iter; protects s_e2 reuse after
        // stage e tile (coalesced)
        const float2* ep2 = (const float2*)(e_row + (size_t)jt * DEPTH);
        for (int idx = tid; idx < tl * 32; idx += 256) {
            int jj = idx >> 5, dd = idx & 31;
            s_e2[jj][dd] = ep2[idx];
        }
        __syncthreads();
        // items: (jj, h), fully serial dot per thread
        for (int item = tid; item < tl * NHEAD; item += 256) {
            int jj = item % tl, h = item / tl;
            int j = jt + jj;
            const float* kp   = k_b + (size_t)j * HH + h * DHEAD;
            const float* qp   = s_q + h * DHEAD;
            const float* qekp = s_qek + h * DHEAD;
            float sum = 0.f;
#pragma unroll
            for (int d = 0; d < DHEAD; d += 4) {
                float4 kv = *(const float4*)(kp + d);
                float4 qv = *(const float4*)(qp + d);
                float4 qe = *(const float4*)(qekp + d);
                float2 e0 = s_e2[jj][d >> 1];
                float2 e1 = s_e2[jj][(d >> 1) + 1];
                sum += qv.x * kv.x + qv.y * kv.y + qv.z * kv.z + qv.w * kv.w
                     + qe.x * e0.x + qe.y * e0.y + qe.z * e1.x + qe.w * e1.y;
            }
            s_scores[h][j] = s_mask[j] ? (sum + s_qbek[h]) * 0.125f : -10000.0f;
        }
    }
    __syncthreads();

    // ---- softmax per head (wave w -> heads w, w+4, w+8); S=160 = 64+64+32 ----
    for (int h = w; h < NHEAD; h += 4) {
        float v0 = s_scores[h][l];
        float v1 = s_scores[h][l + 64];
        float v2 = (l < 32) ? s_scores[h][l + 128] : -INFINITY;
        float mx = fmaxf(v0, fmaxf(v1, v2));
#pragma unroll
        for (int mm = 32; mm >= 1; mm >>= 1) mx = fmaxf(mx, __shfl_xor(mx, mm, 64));
        float e0 = expf(v0 - mx), e1 = expf(v1 - mx);
        float e2 = (l < 32) ? expf(v2 - mx) : 0.f;
        float sm = e0 + e1 + e2;
#pragma unroll
        for (int mm = 32; mm >= 1; mm >>= 1) sm += __shfl_xor(sm, mm, 64);
        float inv = 1.0f / sm;
        s_scores[h][l]      = e0 * inv;
        s_scores[h][l + 64] = e1 * inv;
        if (l < 32) s_scores[h][l + 128] = e2 * inv;
    }
    __syncthreads();

    // ---- pass 2: wave w owns heads 3w..3w+2 fully; lane = channel ----
    {
        int h0 = w * 3;
        float av0 = 0.f, av1 = 0.f, av2 = 0.f;
        float pe0 = 0.f, pe1 = 0.f, pe2 = 0.f;
        const float* vb = v_ws + (size_t)b * SS * HH + h0 * DHEAD + l;
        const float* er = e_row + l;
        const float* p0r = &s_scores[h0][0];
        const float* p1r = &s_scores[h0 + 1][0];
        const float* p2r = &s_scores[h0 + 2][0];
        for (int j = 0; j < SS; j++) {
            float p0 = p0r[j], p1 = p1r[j], p2 = p2r[j];
            const float* vp = vb + (size_t)j * HH;
            av0 += p0 * vp[0];
            av1 += p1 * vp[DHEAD];
            av2 += p2 * vp[2 * DHEAD];
            float ev = er[(size_t)j * DEPTH];
            pe0 += p0 * ev; pe1 += p1 * ev; pe2 += p2 * ev;
        }
        s_pe[h0][l]     = pe0;
        s_pe[h0 + 1][l] = pe1;
        s_pe[h0 + 2][l] = pe2;
        s_q[h0 * DHEAD + l]              = av0;   // s_q reused as ctx_v
        s_q[(h0 + 1) * DHEAD + l]        = av1;
        s_q[(h0 + 2) * DHEAD + l]        = av2;
    }
    __syncthreads();

    // ---- ctx_e = pe_h @ Wev_h + bev ; residual add ----
    for (int mdx = tid; mdx < HH; mdx += 256) {
        int h = mdx >> 6;
        const float* pep = &s_pe[h][0];
        float sum = 0.f;
#pragma unroll
        for (int d = 0; d < DEPTH; d++) sum += pep[d] * Wev[(size_t)d * HH + mdx];
        float ctx = s_q[mdx] + (sum + bev[mdx]);
        s_x[mdx] = token[(size_t)bi * HH + mdx] + ctx;
    }
    __syncthreads();

    // ---- LayerNorm over H ----
    float lsum = 0.f, lsq = 0.f;
    for (int c = tid; c < HH; c += 256) {
        float x = s_x[c];
        lsum += x; lsq += x * x;
    }
#pragma unroll
    for (int mm = 32; mm >= 1; mm >>= 1) {
        lsum += __shfl_xor(lsum, mm, 64);
        lsq  += __shfl_xor(lsq,  mm, 64);
    }
    if (l == 0) { s_red[w] = lsum; s_red[4 + w] = lsq; }
    __syncthreads();
    float tsum = s_red[0] + s_red[1] + s_red[2] + s_red[3];
    float tsq  = s_red[4] + s_red[5] + s_red[6] + s_red[7];
    float mu  = tsum / HH;
    float var = tsq / HH - mu * mu;
    float rstd = rsqrtf(var + EPS_C);
    for (int c = tid; c < HH; c += 256)
        out[(size_t)bi * HH + c] = (s_x[c] - mu) * rstd * ln_g[c] + ln_b[c];
}

extern "C" void kernel_launch(void* const* d_in, const int* in_sizes, int n_in,
                              void* d_out, int out_size, void* d_ws, size_t ws_size,
                              hipStream_t stream) {
    const float* token = (const float*)d_in[0];
    const float* edge  = (const float*)d_in[1];
    const int*   mask  = (const int*)d_in[2];
    const float* Wq = (const float*)d_in[3];  const float* bq = (const float*)d_in[4];
    const float* Wk = (const float*)d_in[5];  const float* bk = (const float*)d_in[6];
    const float* Wv = (const float*)d_in[7];  const float* bv = (const float*)d_in[8];
    const float* Wek = (const float*)d_in[9];  const float* bek = (const float*)d_in[10];
    const float* Wev = (const float*)d_in[11]; const float* bev = (const float*)d_in[12];
    const float* ln_g = (const float*)d_in[13]; const float* ln_b = (const float*)d_in[14];
    float* out = (float*)d_out;

    float* q_ws = (float*)d_ws;
    float* k_ws = q_ws + (size_t)BS * HH;
    float* v_ws = k_ws + (size_t)BS * HH;

    proj_qkv<<<720, 256, 0, stream>>>(token, Wq, bq, Wk, bk, Wv, bv,
                                      q_ws, k_ws, v_ws);
    attn_kernel<<<BS, 256, 0, stream>>>(token, edge, mask, q_ws, k_ws, v_ws,
                                        Wek, bek, Wev, bev, ln_g, ln_b, out);
}